// Round 4
// baseline (265.843 us; speedup 1.0000x reference)
//
#include <hip/hip_runtime.h>

#define BATCH 64
#define M_GT  100
#define M1    101
#define NANCH 8732
#define NF4   (NANCH / 4)          // 2183 float4 per ious row
#define BLOCK 256
#define NPT   2
#define NTILE (BLOCK * NPT)        // 512
#define NX    18                   // ceil(8732/512)
#define NXCD  8

#define B_BLOCKS (NX * BATCH)      // 1152  (argmax+labeled role)
#define A_BLOCKS (BATCH * M1)      // 6464  (ious-row writer role)
#define NBLK     (B_BLOCKS + A_BLOCKS)   // 7616; both ranges %8==0

// Journal:
//  R0: NPT=4, depth~4 stores/wave, 576 blocks      -> baseline, kernel ~100 µs
//  R1: depth-8 store groups, 2x waves              -> neutral (depth/count invariant)
//  R2: nontemporal stores                          -> -35 µs REGRESSION (L2 merge load-bearing)
//  R3: XCD-grouping swizzle                        -> +4 µs (ordering effect real but small)
//  R4 (this): role-split. The untested variable is per-block store-stream
//  contiguity: n-owning threads store at 34,928B stride -> 2KB scattered
//  chunks. Role A writes each (b,m) ious row as ONE contiguous 34KB
//  ascending stream (fill-like); Role B recomputes ious in-register for
//  the argmax (no strided stores) and writes only `labeled`.
__global__ __launch_bounds__(BLOCK) void encode_fused(
    const float* __restrict__ labels,   // [B, M, 5]
    const float* __restrict__ dboxes,   // [N, 4]
    float* __restrict__ out_labeled,    // [B, N, 5]
    float* __restrict__ out_ious)       // [B, M1, N]
{
    __shared__ float4 s_box[M1];
    __shared__ float  s_ar[M1], s_cls[M1];

    const int tid = threadIdx.x;

    if (blockIdx.x >= B_BLOCKS) {
        // ---------------- Role A: contiguous ious-row writer ----------------
        const int raw = blockIdx.x - B_BLOCKS;          // 0..6463
        // XCD grouping: dispatcher assigns XCD by raw%8; give XCD x a
        // contiguous aid range so its L2 evicts one contiguous ~28MB region.
        const int aid = (raw % NXCD) * (A_BLOCKS / NXCD) + raw / NXCD;
        const int b = aid / M1, m = aid % M1;

        float gx1 = 0.f, gy1 = 0.f, gx2 = 0.f, gy2 = 0.f, ga = 0.f;
        bool valid = false;
        if (m >= 1) {
            const float* row = labels + ((size_t)b * M_GT + (m - 1)) * 5;
            gx1 = row[0]; gy1 = row[1]; gx2 = row[2]; gy2 = row[3];
            if (row[4] != 0.0f) { ga = (gx2 - gx1) * (gy2 - gy1); valid = true; }
        }

        float4* const dst = reinterpret_cast<float4*>(out_ious + (size_t)aid * NANCH);
        const float4* const src = reinterpret_cast<const float4*>(dboxes);

        if (!valid) {
            const float4 z = make_float4(0.f, 0.f, 0.f, 0.f);
            for (int f = tid; f < NF4; f += BLOCK) dst[f] = z;   // pad / cls==0 rows: iou == +0
            return;
        }
        for (int f = tid; f < NF4; f += BLOCK) {
            float io[4];
            #pragma unroll
            for (int i = 0; i < 4; ++i) {
                const float4 d = src[4 * f + i];
                const float aa = (d.z - d.x) * (d.w - d.y);
                const float ix1 = fmaxf(gx1, d.x), iy1 = fmaxf(gy1, d.y);
                const float ix2 = fminf(gx2, d.z), iy2 = fminf(gy2, d.w);
                const float iw = fmaxf(ix2 - ix1, 0.0f), ih = fmaxf(iy2 - iy1, 0.0f);
                const float inter = iw * ih;
                io[i] = inter * __builtin_amdgcn_rcpf(ga + aa - inter);
            }
            dst[f] = make_float4(io[0], io[1], io[2], io[3]);    // 4KB/wave-instr, contiguous
        }
        return;
    }

    // ---------------- Role B: argmax + labeled (no ious stores) ----------------
    const int b  = blockIdx.x / NX;
    const int nb = blockIdx.x % NX;

    if (tid < M1) {
        float x1 = 0.f, y1 = 0.f, x2 = 0.f, y2 = 0.f, cls = 0.f;
        float ar = __builtin_inff();                   // pad/invalid -> iou = inter*rcp(inf) = +0
        if (tid >= 1) {
            const float* row = labels + ((size_t)b * M_GT + (tid - 1)) * 5;
            x1 = row[0]; y1 = row[1]; x2 = row[2]; y2 = row[3]; cls = row[4];
            if (cls != 0.0f) ar = (x2 - x1) * (y2 - y1);
        }
        s_box[tid] = make_float4(x1, y1, x2, y2);
        s_ar[tid] = ar; s_cls[tid] = cls;
    }
    __syncthreads();

    const int n0 = nb * NTILE + tid * NPT;
    if (n0 >= NANCH) return;

    float ax1[NPT], ay1[NPT], ax2[NPT], ay2[NPT], aa[NPT];
    #pragma unroll
    for (int i = 0; i < NPT; ++i) {
        const float4 d = *reinterpret_cast<const float4*>(dboxes + (size_t)(n0 + i) * 4);
        ax1[i] = d.x; ay1[i] = d.y; ax2[i] = d.z; ay2[i] = d.w;
        aa[i]  = (d.z - d.x) * (d.w - d.y);
    }

    // best=-1: pad rows give iou=+0; strict > = numpy first-occurrence argmax.
    float best[NPT]; int besti[NPT];
    #pragma unroll
    for (int i = 0; i < NPT; ++i) { best[i] = -1.0f; besti[i] = 0; }

    #pragma unroll 4
    for (int m = 0; m < M1; ++m) {
        const float4 g = s_box[m];
        const float ga = s_ar[m];
        #pragma unroll
        for (int i = 0; i < NPT; ++i) {
            const float ix1 = fmaxf(g.x, ax1[i]), iy1 = fmaxf(g.y, ay1[i]);
            const float ix2 = fminf(g.z, ax2[i]), iy2 = fminf(g.w, ay2[i]);
            const float iw = fmaxf(ix2 - ix1, 0.0f), ih = fmaxf(iy2 - iy1, 0.0f);
            const float inter = iw * ih;
            const float iou = inter * __builtin_amdgcn_rcpf(ga + aa[i] - inter);
            if (iou > best[i]) { best[i] = iou; besti[i] = m; }
        }
    }

    // Epilogue
    float lw[NPT * 5];
    #pragma unroll
    for (int i = 0; i < NPT; ++i) {
        const int idx = (best[i] > 0.5f) ? besti[i] : 0;
        float ox = 0.f, oy = 0.f, ow = 0.f, oh = 0.f, pcls = 0.f;
        if (idx != 0) {   // iou>0.5 winner is always a valid (cls!=0) row
            const float4 t = s_box[idx];
            const float aw = ax2[i] - ax1[i], ah = ay2[i] - ay1[i];
            ox = (0.5f * (t.x + t.z) - 0.5f * (ax1[i] + ax2[i])) / aw;
            oy = (0.5f * (t.y + t.w) - 0.5f * (ay1[i] + ay2[i])) / ah;
            ow = __logf((t.z - t.x) / aw);
            oh = __logf((t.w - t.y) / ah);
            pcls = s_cls[idx];
        }
        lw[i * 5 + 0] = ox; lw[i * 5 + 1] = oy; lw[i * 5 + 2] = ow;
        lw[i * 5 + 3] = oh; lw[i * 5 + 4] = pcls;
    }
    // 10 contiguous floats = 40B, 8B-aligned (n0 even) -> 5 dwordx2 stores
    float* lrow = out_labeled + ((size_t)b * NANCH + n0) * 5;
    #pragma unroll
    for (int k = 0; k < 5; ++k) {
        float2 v; v.x = lw[k * 2]; v.y = lw[k * 2 + 1];
        *reinterpret_cast<float2*>(lrow + k * 2) = v;
    }
}

extern "C" void kernel_launch(void* const* d_in, const int* in_sizes, int n_in,
                              void* d_out, int out_size, void* d_ws, size_t ws_size,
                              hipStream_t stream) {
    const float* labels = (const float*)d_in[0];
    const float* dboxes = (const float*)d_in[1];
    float* out_labeled = (float*)d_out;
    float* out_ious    = out_labeled + (size_t)BATCH * NANCH * 5;

    encode_fused<<<dim3(NBLK), dim3(BLOCK), 0, stream>>>(labels, dboxes, out_labeled, out_ious);
}

// Round 5
// 264.849 us; speedup vs baseline: 1.0038x; 1.0038x over previous
//
#include <hip/hip_runtime.h>

#define BATCH 64
#define M_GT  100
#define M1    101
#define NANCH 8732
#define BLOCK 256
#define NPT   2                    // anchors per thread -> dwordx2 stores
#define NTILE (BLOCK * NPT)        // 512
#define NX    18                   // ceil(8732/512)
#define NBLK  (NX * BATCH)         // 1152 blocks = 4608 waves
#define NXCD  8
#define GROUP 8                    // rows per store burst
#define MBULK ((M1 / GROUP) * GROUP)   // 96
#define MTAIL (M1 - MBULK)             // 5

// Journal:
//  R0: NPT=4, 576 blocks                    -> 245.7 (baseline)
//  R1: NPT=2, depth-8 groups, 1152 blocks   -> 244.4 neutral (depth/width/count invariant)
//  R2: nontemporal stores                   -> 279.3 REGRESSION (L2 merge load-bearing)
//  R3: XCD-grouping swizzle                 -> 240.4 (+4, best)
//  R4: role-split contiguous row writer     -> 265.8 REGRESSION (contiguity NOT the lever)
//  R5 (this): DIAGNOSTIC. Run the m-loop + ious stores TWICE (byte-identical
//  rewrite, memory-clobber between passes). Pushes encode_fused into the
//  top-5 counter rows (first direct VALUBusy/WRITE_SIZE/Occupancy read) and
//  Delta-dur vs R3 = true marginal cost of one compute+store pass.
__global__ __launch_bounds__(BLOCK) void encode_fused(
    const float* __restrict__ labels,   // [B, M, 5]
    const float* __restrict__ dboxes,   // [N, 4]
    float* __restrict__ out_labeled,    // [B, N, 5]
    float* __restrict__ out_ious)       // [B, M1, N]
{
    __shared__ float4 s_box[M1];
    __shared__ float  s_ar[M1], s_cls[M1];

    const int tid = threadIdx.x;
    // XCD-grouping swizzle (R3): all NX chunks of each b on one XCD.
    const int x  = blockIdx.x % NXCD;
    const int j  = blockIdx.x / NXCD;
    const int b  = x * (BATCH / NXCD) + j / NX;
    const int nb = j % NX;

    if (tid < M1) {
        float x1 = 0.f, y1 = 0.f, x2 = 0.f, y2 = 0.f, cls = 0.f;
        float ar = __builtin_inff();   // pad/invalid -> iou = inter*rcp(inf) = +0
        if (tid >= 1) {
            const float* row = labels + ((size_t)b * M_GT + (tid - 1)) * 5;
            x1 = row[0]; y1 = row[1]; x2 = row[2]; y2 = row[3]; cls = row[4];
            if (cls != 0.0f) ar = (x2 - x1) * (y2 - y1);
        }
        s_box[tid] = make_float4(x1, y1, x2, y2);
        s_ar[tid] = ar; s_cls[tid] = cls;
    }
    __syncthreads();

    const int n0 = nb * NTILE + tid * NPT;
    if (n0 >= NANCH) return;

    float ax1[NPT], ay1[NPT], ax2[NPT], ay2[NPT], aa[NPT];
    #pragma unroll
    for (int i = 0; i < NPT; ++i) {
        const float4 d = *reinterpret_cast<const float4*>(dboxes + (size_t)(n0 + i) * 4);
        ax1[i] = d.x; ay1[i] = d.y; ax2[i] = d.z; ay2[i] = d.w;
        aa[i]  = (d.z - d.x) * (d.w - d.y);
    }

    float* const irow = out_ious + (size_t)b * M1 * NANCH + n0;

    float best[NPT]; int besti[NPT];

    // ---- DIAGNOSTIC double pass: identical work, identical bytes. ----
    #pragma unroll 1
    for (int pass = 0; pass < 2; ++pass) {
        #pragma unroll
        for (int i = 0; i < NPT; ++i) { best[i] = -1.0f; besti[i] = 0; }

        auto row_body = [&](int m) {
            const float4 g = s_box[m];      // ds_read_b128 broadcast
            const float ga = s_ar[m];       // ds_read_b32 broadcast
            float iou[NPT];
            #pragma unroll
            for (int i = 0; i < NPT; ++i) {
                const float ix1 = fmaxf(g.x, ax1[i]), iy1 = fmaxf(g.y, ay1[i]);
                const float ix2 = fminf(g.z, ax2[i]), iy2 = fminf(g.w, ay2[i]);
                const float iw = fmaxf(ix2 - ix1, 0.0f), ih = fmaxf(iy2 - iy1, 0.0f);
                const float inter = iw * ih;
                iou[i] = inter * __builtin_amdgcn_rcpf(ga + aa[i] - inter);
                if (iou[i] > best[i]) { best[i] = iou[i]; besti[i] = m; }
            }
            float2 w; w.x = iou[0]; w.y = iou[1];
            *reinterpret_cast<float2*>(irow + (size_t)m * NANCH) = w;
        };

        for (int mg = 0; mg < MBULK; mg += GROUP) {
            #pragma unroll
            for (int r = 0; r < GROUP; ++r) row_body(mg + r);
        }
        #pragma unroll
        for (int r = 0; r < MTAIL; ++r) row_body(MBULK + r);

        // Full barrier: pass-0 stores must be emitted; no cross-pass merge.
        asm volatile("" ::: "memory");
    }

    // Epilogue (argmax state from pass 1 == pass 0, deterministic)
    float lw[NPT * 5];
    #pragma unroll
    for (int i = 0; i < NPT; ++i) {
        const int idx = (best[i] > 0.5f) ? besti[i] : 0;
        float ox = 0.f, oy = 0.f, ow = 0.f, oh = 0.f, pcls = 0.f;
        if (idx != 0) {   // iou>0.5 winner is always a valid (cls!=0) row
            const float4 t = s_box[idx];
            const float aw = ax2[i] - ax1[i], ah = ay2[i] - ay1[i];
            ox = (0.5f * (t.x + t.z) - 0.5f * (ax1[i] + ax2[i])) / aw;
            oy = (0.5f * (t.y + t.w) - 0.5f * (ay1[i] + ay2[i])) / ah;
            ow = __logf((t.z - t.x) / aw);
            oh = __logf((t.w - t.y) / ah);
            pcls = s_cls[idx];
        }
        lw[i * 5 + 0] = ox; lw[i * 5 + 1] = oy; lw[i * 5 + 2] = ow;
        lw[i * 5 + 3] = oh; lw[i * 5 + 4] = pcls;
    }
    float* lrow = out_labeled + ((size_t)b * NANCH + n0) * 5;
    #pragma unroll
    for (int k = 0; k < 5; ++k) {
        float2 v; v.x = lw[k * 2]; v.y = lw[k * 2 + 1];
        *reinterpret_cast<float2*>(lrow + k * 2) = v;
    }
}

extern "C" void kernel_launch(void* const* d_in, const int* in_sizes, int n_in,
                              void* d_out, int out_size, void* d_ws, size_t ws_size,
                              hipStream_t stream) {
    const float* labels = (const float*)d_in[0];
    const float* dboxes = (const float*)d_in[1];
    float* out_labeled = (float*)d_out;
    float* out_ious    = out_labeled + (size_t)BATCH * NANCH * 5;

    encode_fused<<<dim3(NBLK), dim3(BLOCK), 0, stream>>>(labels, dboxes, out_labeled, out_ious);
}